// Round 1
// baseline (99.679 us; speedup 1.0000x reference)
//
#include <hip/hip_runtime.h>
#include <math.h>

#define B_   256
#define IN_  512
#define OUT_ 512
#define E_   256
#define DELTA_ 0.1f
#define LN_EPS_ 1e-5f

// ---------------------------------------------------------------------------
// K1: scores[i][o] = pred_emb[i,:]·attn_w[o,:] + attn_b[o]; row-LN over o;
//     sigmoid. Emits SoA planes:
//       wA[i][o] = W[o][i]
//       vA[i][o] = DELTA * |W[o][i]| * sig[i][o]   (DELTA pre-folded)
// 512 threads, 4 i-rows per block, grid 128. Each thread owns one o for all
// 4 rows -> attn_w float4 reused 4x in regs; attn_w L2 traffic halved vs
// the 2-row version (128 blocks x 512 KB = 67 MB).
// ---------------------------------------------------------------------------
__global__ __launch_bounds__(512)
void k1_scores_ln_sig(const float* __restrict__ pred_emb,
                      const float* __restrict__ attn_w,
                      const float* __restrict__ attn_b,
                      const float* __restrict__ ln_g,
                      const float* __restrict__ ln_b,
                      const float* __restrict__ weights,
                      float* __restrict__ wA,
                      float* __restrict__ vA) {
    __shared__ float pe[4][E_];        // 4 KB
    __shared__ float red[8][4][2];     // [wave][row][{s1,s2}]
    __shared__ float smu[4], srs[4];

    const int t    = threadIdx.x;      // 0..511
    const int lane = t & 63;
    const int wid  = t >> 6;           // 0..7
    const int i0   = blockIdx.x * 4;
    const int o    = t;

    // stage 4 pred_emb rows: 512 threads load 1024 floats
    #pragma unroll
    for (int k = 0; k < 2; ++k) {
        int p = t + 512 * k;
        pe[p >> 8][p & 255] = pred_emb[(size_t)(i0 + (p >> 8)) * E_ + (p & 255)];
    }
    __syncthreads();

    const float4* p0 = reinterpret_cast<const float4*>(pe[0]);
    const float4* p1 = reinterpret_cast<const float4*>(pe[1]);
    const float4* p2 = reinterpret_cast<const float4*>(pe[2]);
    const float4* p3 = reinterpret_cast<const float4*>(pe[3]);
    const float4* wrow = reinterpret_cast<const float4*>(attn_w + (size_t)o * E_);

    float a0 = 0.f, a1 = 0.f, a2 = 0.f, a3 = 0.f;
    #pragma unroll 8
    for (int e4 = 0; e4 < E_ / 4; ++e4) {
        float4 w4 = wrow[e4];
        float4 q0 = p0[e4];
        float4 q1 = p1[e4];
        float4 q2 = p2[e4];
        float4 q3 = p3[e4];
        a0 += q0.x * w4.x + q0.y * w4.y + q0.z * w4.z + q0.w * w4.w;
        a1 += q1.x * w4.x + q1.y * w4.y + q1.z * w4.z + q1.w * w4.w;
        a2 += q2.x * w4.x + q2.y * w4.y + q2.z * w4.z + q2.w * w4.w;
        a3 += q3.x * w4.x + q3.y * w4.y + q3.z * w4.z + q3.w * w4.w;
    }
    const float bo = attn_b[o];
    a0 += bo; a1 += bo; a2 += bo; a3 += bo;

    // LN stats per row over 512 o-values (one per thread)
    {
        float s10 = a0, s20 = a0 * a0;
        float s11 = a1, s21 = a1 * a1;
        float s12 = a2, s22 = a2 * a2;
        float s13 = a3, s23 = a3 * a3;
        #pragma unroll
        for (int off = 32; off > 0; off >>= 1) {
            s10 += __shfl_down(s10, off); s20 += __shfl_down(s20, off);
            s11 += __shfl_down(s11, off); s21 += __shfl_down(s21, off);
            s12 += __shfl_down(s12, off); s22 += __shfl_down(s22, off);
            s13 += __shfl_down(s13, off); s23 += __shfl_down(s23, off);
        }
        if (lane == 0) {
            red[wid][0][0] = s10; red[wid][0][1] = s20;
            red[wid][1][0] = s11; red[wid][1][1] = s21;
            red[wid][2][0] = s12; red[wid][2][1] = s22;
            red[wid][3][0] = s13; red[wid][3][1] = s23;
        }
    }
    __syncthreads();
    if (t < 4) {
        float s1 = 0.f, s2 = 0.f;
        #pragma unroll
        for (int w = 0; w < 8; ++w) { s1 += red[w][t][0]; s2 += red[w][t][1]; }
        float mu  = s1 / (float)OUT_;
        float var = s2 / (float)OUT_ - mu * mu;
        smu[t] = mu;
        srs[t] = rsqrtf(var + LN_EPS_);
    }
    __syncthreads();

    const float g  = ln_g[o];
    const float bb = ln_b[o];
    float z0 = (a0 - smu[0]) * srs[0] * g + bb;
    float z1 = (a1 - smu[1]) * srs[1] * g + bb;
    float z2 = (a2 - smu[2]) * srs[2] * g + bb;
    float z3 = (a3 - smu[3]) * srs[3] * g + bb;
    float sg0 = 1.f / (1.f + expf(-z0));
    float sg1 = 1.f / (1.f + expf(-z1));
    float sg2 = 1.f / (1.f + expf(-z2));
    float sg3 = 1.f / (1.f + expf(-z3));

    // adjacent i -> one float4 load of weights[o][i0..i0+3]
    float4 w4 = *reinterpret_cast<const float4*>(weights + (size_t)o * IN_ + i0);
    wA[(size_t)(i0 + 0) * OUT_ + o] = w4.x;
    wA[(size_t)(i0 + 1) * OUT_ + o] = w4.y;
    wA[(size_t)(i0 + 2) * OUT_ + o] = w4.z;
    wA[(size_t)(i0 + 3) * OUT_ + o] = w4.w;
    vA[(size_t)(i0 + 0) * OUT_ + o] = DELTA_ * fabsf(w4.x) * sg0;
    vA[(size_t)(i0 + 1) * OUT_ + o] = DELTA_ * fabsf(w4.y) * sg1;
    vA[(size_t)(i0 + 2) * OUT_ + o] = DELTA_ * fabsf(w4.z) * sg2;
    vA[(size_t)(i0 + 3) * OUT_ + o] = DELTA_ * fabsf(w4.w) * sg3;
}

// ---------------------------------------------------------------------------
// K2: split-K partials. Tile 64b x 64o x 64i per block, 256 threads, each
// thread owns a 4b x 4o register tile (16 outputs) -> LDS bytes/element
// drops 6 -> 3 (12 x b128 per 64 elements). SK=8, grid (8,4,8) = 256 blocks
// = 1 block/CU. SoA LDS planes (w, v) so an o-quad is one b128 read with
// only 2-way bank aliasing (free); x rows padded to 17 float4 so the four
// b-row reads hit disjoint bank quads. DELTA is pre-folded into v, so:
//   lin = d - s,  m already DELTA-scaled.
// ---------------------------------------------------------------------------
#define K2_SK 8
#define K2_CH 64
#define K2_BO (B_ * OUT_)   // 131072

__global__ __launch_bounds__(256)
void k2_partials(const float* __restrict__ x,
                 const float* __restrict__ wA,
                 const float* __restrict__ vA,
                 float* __restrict__ plin,
                 float* __restrict__ pmax) {
    __shared__ float4 xs [64 * 17];    // 17.4 KB
    __shared__ float4 wss[64 * 17];    // 17.4 KB
    __shared__ float4 vss[64 * 17];    // 17.4 KB

    const int t  = threadIdx.x;
    const int oq = t & 15;             // o-quad: o = o0 + oq*4 + {0..3}
    const int br = t >> 4;             // b rows: br, br+16, br+32, br+48
    const int o0 = blockIdx.x * 64;
    const int b0 = blockIdx.y * 64;
    const int i0 = blockIdx.z * K2_CH;

    // stage: 64 rows x 16 float4 per plane, coalesced 256 B row segments
    #pragma unroll
    for (int k = 0; k < 4; ++k) {
        int p   = t + k * 256;         // 0..1023
        int row = p >> 4;
        int c4  = p & 15;
        xs [row * 17 + c4] = *reinterpret_cast<const float4*>(
            x  + (size_t)(b0 + row) * IN_  + i0 + c4 * 4);
        wss[row * 17 + c4] = *reinterpret_cast<const float4*>(
            wA + (size_t)(i0 + row) * OUT_ + o0 + c4 * 4);
        vss[row * 17 + c4] = *reinterpret_cast<const float4*>(
            vA + (size_t)(i0 + row) * OUT_ + o0 + c4 * 4);
    }
    __syncthreads();

    float d[4][4], s[4][4], m[4][4];
    #pragma unroll
    for (int b = 0; b < 4; ++b)
        #pragma unroll
        for (int oo = 0; oo < 4; ++oo) {
            d[b][oo] = 0.f; s[b][oo] = 0.f; m[b][oo] = -INFINITY;
        }

    #pragma unroll 2
    for (int i4 = 0; i4 < K2_CH / 4; ++i4) {
        float4 xv0 = xs[(br +  0) * 17 + i4];
        float4 xv1 = xs[(br + 16) * 17 + i4];
        float4 xv2 = xs[(br + 32) * 17 + i4];
        float4 xv3 = xs[(br + 48) * 17 + i4];
        float xr[4][4] = {{xv0.x, xv0.y, xv0.z, xv0.w},
                          {xv1.x, xv1.y, xv1.z, xv1.w},
                          {xv2.x, xv2.y, xv2.z, xv2.w},
                          {xv3.x, xv3.y, xv3.z, xv3.w}};
        float ur[4][4];
        #pragma unroll
        for (int b = 0; b < 4; ++b)
            #pragma unroll
            for (int ii = 0; ii < 4; ++ii)
                ur[b][ii] = xr[b][ii] * fabsf(xr[b][ii]);

        #pragma unroll
        for (int ii = 0; ii < 4; ++ii) {
            float4 w4 = wss[(i4 * 4 + ii) * 17 + oq];
            float4 v4 = vss[(i4 * 4 + ii) * 17 + oq];
            #pragma unroll
            for (int b = 0; b < 4; ++b) {
                float xb = xr[b][ii];
                float ub = ur[b][ii];
                float p_;
                d[b][0] = fmaf(xb, w4.x, d[b][0]); p_ = ub * v4.x; s[b][0] += p_; m[b][0] = fmaxf(m[b][0], p_);
                d[b][1] = fmaf(xb, w4.y, d[b][1]); p_ = ub * v4.y; s[b][1] += p_; m[b][1] = fmaxf(m[b][1], p_);
                d[b][2] = fmaf(xb, w4.z, d[b][2]); p_ = ub * v4.z; s[b][2] += p_; m[b][2] = fmaxf(m[b][2], p_);
                d[b][3] = fmaf(xb, w4.w, d[b][3]); p_ = ub * v4.w; s[b][3] += p_; m[b][3] = fmaxf(m[b][3], p_);
            }
        }
    }

    #pragma unroll
    for (int b = 0; b < 4; ++b) {
        const int row = b0 + br + 16 * b;
        const size_t idx = ((size_t)blockIdx.z * B_ + row) * OUT_ + o0 + oq * 4;
        *reinterpret_cast<float4*>(plin + idx) =
            make_float4(d[b][0] - s[b][0], d[b][1] - s[b][1],
                        d[b][2] - s[b][2], d[b][3] - s[b][3]);
        *reinterpret_cast<float4*>(pmax + idx) =
            make_float4(m[b][0], m[b][1], m[b][2], m[b][3]);
    }
}

// ---------------------------------------------------------------------------
// K3: combine 8 split-K partials, float4-wide. out = sum lin + max m
// (m already DELTA-scaled).
// ---------------------------------------------------------------------------
__global__ __launch_bounds__(256)
void k3_combine(const float4* __restrict__ plin4,
                const float4* __restrict__ pmax4,
                float4* __restrict__ out4) {
    const int g = blockIdx.x * 256 + threadIdx.x;   // 0..32767
    const int Q = K2_BO / 4;                        // 32768
    float4 l  = plin4[g];
    float4 mx = pmax4[g];
    #pragma unroll
    for (int p = 1; p < K2_SK; ++p) {
        float4 lp = plin4[(size_t)p * Q + g];
        float4 mp = pmax4[(size_t)p * Q + g];
        l.x += lp.x; l.y += lp.y; l.z += lp.z; l.w += lp.w;
        mx.x = fmaxf(mx.x, mp.x); mx.y = fmaxf(mx.y, mp.y);
        mx.z = fmaxf(mx.z, mp.z); mx.w = fmaxf(mx.w, mp.w);
    }
    out4[g] = make_float4(l.x + mx.x, l.y + mx.y, l.z + mx.z, l.w + mx.w);
}

// ---------------------------------------------------------------------------
extern "C" void kernel_launch(void* const* d_in, const int* in_sizes, int n_in,
                              void* d_out, int out_size, void* d_ws, size_t ws_size,
                              hipStream_t stream) {
    const float* x        = (const float*)d_in[0];
    const float* weights  = (const float*)d_in[1];
    const float* pred_emb = (const float*)d_in[2];
    const float* attn_w   = (const float*)d_in[3];
    const float* attn_b   = (const float*)d_in[4];
    const float* ln_g     = (const float*)d_in[5];
    const float* ln_b     = (const float*)d_in[6];

    // workspace layout: wA (1 MB) | vA (1 MB) | plin (4 MB) | pmax (4 MB)
    float* wA   = (float*)d_ws;
    float* vA   = wA + (size_t)IN_ * OUT_;
    float* plin = vA + (size_t)IN_ * OUT_;
    float* pmax = plin + (size_t)K2_SK * K2_BO;

    k1_scores_ln_sig<<<IN_ / 4, 512, 0, stream>>>(
        pred_emb, attn_w, attn_b, ln_g, ln_b, weights, wA, vA);

    k2_partials<<<dim3(OUT_ / 64, B_ / 64, K2_SK), 256, 0, stream>>>(
        x, wA, vA, plin, pmax);

    k3_combine<<<K2_BO / 4 / 256, 256, 0, stream>>>(
        (const float4*)plin, (const float4*)pmax, (float4*)d_out);
}